// Round 6
// baseline (90713.245 us; speedup 1.0000x reference)
//
#include <hip/hip_runtime.h>
#include <cstdint>

// ---------------------------------------------------------------------------
// HierarchicalGraphMemoryNetwork on MI355X — round 6
//
// Scan rewritten around MFMA (v_mfma_f32_16x16x32_f16):
//  - The 512KB Whh matrix CANNOT be register-resident (= entire 2048-reg/CU
//    file). Rounds 1-5 were LDS-instruction-rate-bound (~48 b128/thread/step
//    ~ 12cy each = 4400cy/step).
//  - New: 256 threads/scan; wave owns 256 gate rows = 16 MFMA tiles.
//    Tiles 0-7: A-fragments pinned in 256 AGPRs (asm "+a"; MFMA reads AGPR
//    directly). Tiles 8-15: streamed from L2 each step (volatile asm
//    global_load_dwordx4 + manual vmcnt + sched_barrier). LDS carries only
//    h-broadcast and z exchange (~30 instr/thread/step).
//  - B operand = h replicated across all 16 MFMA columns -> one 16B broadcast
//    read per k-chunk; D lane layout (col=lane&15 — m89-verified) means all
//    lanes hold valid z; lanes (l&15)==0 write z to LDS.
// ---------------------------------------------------------------------------

#define T_LEN 8192
#define IN_F  256
#define HID   256
#define GATE  1024
#define NREL  4
#define OUT_N 256

typedef _Float16 f16x8 __attribute__((ext_vector_type(8)));
typedef float    f32x4 __attribute__((ext_vector_type(4)));
typedef uint32_t u32x4 __attribute__((ext_vector_type(4)));

__device__ __forceinline__ f32x4 mfma16(u32x4 a, u32x4 b, f32x4 c) {
  return __builtin_amdgcn_mfma_f32_16x16x32_f16(
      __builtin_bit_cast(f16x8, a), __builtin_bit_cast(f16x8, b), c, 0, 0, 0);
}

__device__ __forceinline__ float fsig(float x) { return 1.f / (1.f + __expf(-x)); }
__device__ __forceinline__ float ftanh(float x) { return 2.f / (1.f + __expf(-2.f * x)) - 1.f; }

// ------------------------------- GEMM --------------------------------------
__global__ __launch_bounds__(256) void gemm_kernel(
    const float* __restrict__ A, int lda,
    const float* __restrict__ W, int ldw,
    const float* __restrict__ bias,
    const float* addC,
    float* C, int ldc, int M, int N, int K) {
  __shared__ float As[16][64];
  __shared__ float Bs[16][64];
  const int tid = threadIdx.x;
  const int tx = tid & 15, ty = tid >> 4;
  const int m0 = blockIdx.y * 64, n0 = blockIdx.x * 64;
  const int lr = tid >> 2;
  const int lc = (tid & 3) * 4;
  float acc[4][4] = {};
  for (int k0 = 0; k0 < K; k0 += 16) {
    float4 av = *(const float4*)&A[(size_t)(m0 + lr) * lda + k0 + lc];
    float4 wv = *(const float4*)&W[(size_t)(n0 + lr) * ldw + k0 + lc];
    As[lc + 0][lr] = av.x; As[lc + 1][lr] = av.y; As[lc + 2][lr] = av.z; As[lc + 3][lr] = av.w;
    Bs[lc + 0][lr] = wv.x; Bs[lc + 1][lr] = wv.y; Bs[lc + 2][lr] = wv.z; Bs[lc + 3][lr] = wv.w;
    __syncthreads();
#pragma unroll
    for (int k = 0; k < 16; ++k) {
      float a[4], b[4];
#pragma unroll
      for (int i = 0; i < 4; ++i) a[i] = As[k][ty * 4 + i];
#pragma unroll
      for (int jj = 0; jj < 4; ++jj) b[jj] = Bs[k][tx * 4 + jj];
#pragma unroll
      for (int i = 0; i < 4; ++i)
#pragma unroll
        for (int jj = 0; jj < 4; ++jj) acc[i][jj] += a[i] * b[jj];
    }
    __syncthreads();
  }
#pragma unroll
  for (int i = 0; i < 4; ++i) {
    int m = m0 + ty * 4 + i;
#pragma unroll
    for (int jj = 0; jj < 4; ++jj) {
      int n = n0 + tx * 4 + jj;
      float v = acc[i][jj];
      if (bias) v += bias[n];
      if (addC) v += addC[(size_t)m * ldc + n];
      C[(size_t)m * ldc + n] = v;
    }
  }
}

// ------------------------------ gather -------------------------------------
__global__ void gather_kernel(const float* __restrict__ nodes,
                              const int* __restrict__ edges,
                              float* __restrict__ pair) {
  int t = blockIdx.x;
  int c = threadIdx.x;
  int e = edges[t * 2 + (c >> 8)];
  pair[(size_t)t * 512 + c] = nodes[(size_t)e * 256 + (c & 255)];
}

// --------------------------- fragment prep ---------------------------------
// Rearrange Whh (f32 [1024][256]) into f16 MFMA A-fragments.
// A-layout for v_mfma_f32_16x16x32_f16: lane l holds A[row=l&15][k=8*(l>>4)+e],
// e=0..7 packed as consecutive f16 (4 dwords).
// Buffer layout (u32x4 units): idx = ((w*16 + rt)*8 + kc)*64 + l
//   row = w*256 + rt*16 + (l&15); k = kc*32 + 8*(l>>4) + e.
struct PrepSrcs { const float* p[9]; };

__global__ __launch_bounds__(256) void prep_frags(PrepSrcs s, u32x4* __restrict__ outAll) {
  int id = blockIdx.x * 256 + threadIdx.x;      // 0 .. 9*32768-1
  int mat = id >> 15;
  int r   = id & 32767;
  int l   = r & 63;
  int kc  = (r >> 6) & 7;
  int rt  = (r >> 9) & 15;
  int w   = r >> 13;
  const float* W = s.p[mat];
  int row = w * 256 + rt * 16 + (l & 15);
  int kb  = kc * 32 + ((l >> 4) << 3);
  const float* src = W + (size_t)row * 256 + kb;
  uint32_t dw[4];
#pragma unroll
  for (int i = 0; i < 4; ++i) {
    uint16_t lo = __builtin_bit_cast(uint16_t, (_Float16)src[2 * i]);
    uint16_t hi = __builtin_bit_cast(uint16_t, (_Float16)src[2 * i + 1]);
    dw[i] = (uint32_t)lo | ((uint32_t)hi << 16);
  }
  u32x4 v = {dw[0], dw[1], dw[2], dw[3]};
  outAll[id] = v;
}

// ------------------------------ LSTM scan ----------------------------------
struct ScanDesc {
  const float* Xp;        // [T][1024] fp32 input projection (incl. bias)
  const u32x4* Wf;        // fragment buffer (32768 u32x4)
  float* out;             // h output
  int rev;
  int hstride;
};

// volatile asm load: cannot be hoisted out of the loop (weights re-stream from
// L2 each step by design). Manual vmcnt + sched_barrier before use (rule #18).
#define GLD(dst, base, OFF) \
  asm volatile("global_load_dwordx4 %0, %1, off offset:" OFF : "=v"(dst) : "v"(base))

#define SLOAD8(S, BA, BB) \
  GLD(S##_0, BA, "0"); GLD(S##_1, BA, "1024"); GLD(S##_2, BA, "2048"); GLD(S##_3, BA, "3072"); \
  GLD(S##_4, BB, "0"); GLD(S##_5, BB, "1024"); GLD(S##_6, BB, "2048"); GLD(S##_7, BB, "3072");

__global__ __launch_bounds__(256)
__attribute__((amdgpu_waves_per_eu(1, 1)))
void lstm_scan_mfma(ScanDesc d0, ScanDesc d1, ScanDesc d2, int T) {
  ScanDesc d;
  if (blockIdx.x == 0) d = d0;
  else if (blockIdx.x == 1) d = d1;
  else d = d2;
  const float* __restrict__ Xp = d.Xp;
  float* __restrict__ out = d.out;
  const int rev = d.rev, hstride = d.hstride;

  const int j = threadIdx.x;            // 0..255
  const int w = j >> 6, l = j & 63;

  __shared__ __align__(16) float z_sh[1024];
  __shared__ __align__(16) _Float16 h_sh[256];

  const u32x4* fb = d.Wf + (size_t)w * 8192 + l;

  // ---- AGPR-resident tiles 0..7 (64 fragments = 256 AGPRs) ----
#define AG_DECL(rt, kc) u32x4 A##rt##_##kc = fb[((rt) * 8 + (kc)) * 64];
#define AG_ROW(rt) AG_DECL(rt,0) AG_DECL(rt,1) AG_DECL(rt,2) AG_DECL(rt,3) \
                   AG_DECL(rt,4) AG_DECL(rt,5) AG_DECL(rt,6) AG_DECL(rt,7)
  AG_ROW(0) AG_ROW(1) AG_ROW(2) AG_ROW(3) AG_ROW(4) AG_ROW(5) AG_ROW(6) AG_ROW(7)
#define AG_PIN(rt, kc) asm volatile("" : "+a"(A##rt##_##kc));
#define AG_PINR(rt) AG_PIN(rt,0) AG_PIN(rt,1) AG_PIN(rt,2) AG_PIN(rt,3) \
                    AG_PIN(rt,4) AG_PIN(rt,5) AG_PIN(rt,6) AG_PIN(rt,7)
  AG_PINR(0) AG_PINR(1) AG_PINR(2) AG_PINR(3) AG_PINR(4) AG_PINR(5) AG_PINR(6) AG_PINR(7)

  // ---- stream base pointers for tiles 8..15 (two halves each, offset<4096) ----
  const u32x4* sb8a  = fb + 8  * 512; const u32x4* sb8b  = sb8a  + 256;
  const u32x4* sb9a  = fb + 9  * 512; const u32x4* sb9b  = sb9a  + 256;
  const u32x4* sb10a = fb + 10 * 512; const u32x4* sb10b = sb10a + 256;
  const u32x4* sb11a = fb + 11 * 512; const u32x4* sb11b = sb11a + 256;
  const u32x4* sb12a = fb + 12 * 512; const u32x4* sb12b = sb12a + 256;
  const u32x4* sb13a = fb + 13 * 512; const u32x4* sb13b = sb13a + 256;
  const u32x4* sb14a = fb + 14 * 512; const u32x4* sb14b = sb14a + 256;
  const u32x4* sb15a = fb + 15 * 512; const u32x4* sb15b = sb15a + 256;

  if (j < 128) ((uint32_t*)h_sh)[j] = 0u;
  float c = 0.f;
  const int t0 = rev ? (T - 1) : 0;
  float xpi = Xp[(size_t)t0 * GATE + j];
  float xpf = Xp[(size_t)t0 * GATE + j + 256];
  float xpg = Xp[(size_t)t0 * GATE + j + 512];
  float xpo = Xp[(size_t)t0 * GATE + j + 768];
  __syncthreads();

  for (int s = 0; s < T; ++s) {
    const int t = rev ? (T - 1 - s) : s;

    u32x4 S0_0, S0_1, S0_2, S0_3, S0_4, S0_5, S0_6, S0_7;
    u32x4 S1_0, S1_1, S1_2, S1_3, S1_4, S1_5, S1_6, S1_7;
    u32x4 S2_0, S2_1, S2_2, S2_3, S2_4, S2_5, S2_6, S2_7;
    u32x4 S3_0, S3_1, S3_2, S3_3, S3_4, S3_5, S3_6, S3_7;

    // issue batch 1 (tiles 8..11) early
    SLOAD8(S0, sb8a,  sb8b)
    SLOAD8(S1, sb9a,  sb9b)
    SLOAD8(S2, sb10a, sb10b)
    SLOAD8(S3, sb11a, sb11b)

    // h fragments: one 16B broadcast slice per k-chunk
    const char* hbase = (const char*)h_sh + ((l >> 4) << 4);
    u32x4 hb0 = *(const u32x4*)(hbase + 0);
    u32x4 hb1 = *(const u32x4*)(hbase + 64);
    u32x4 hb2 = *(const u32x4*)(hbase + 128);
    u32x4 hb3 = *(const u32x4*)(hbase + 192);
    u32x4 hb4 = *(const u32x4*)(hbase + 256);
    u32x4 hb5 = *(const u32x4*)(hbase + 320);
    u32x4 hb6 = *(const u32x4*)(hbase + 384);
    u32x4 hb7 = *(const u32x4*)(hbase + 448);

    // AGPR tiles 0..7, k-chunk-outer (8 independent chains)
    f32x4 acc0 = {0.f,0.f,0.f,0.f}, acc1 = {0.f,0.f,0.f,0.f};
    f32x4 acc2 = {0.f,0.f,0.f,0.f}, acc3 = {0.f,0.f,0.f,0.f};
    f32x4 acc4 = {0.f,0.f,0.f,0.f}, acc5 = {0.f,0.f,0.f,0.f};
    f32x4 acc6 = {0.f,0.f,0.f,0.f}, acc7 = {0.f,0.f,0.f,0.f};
#define MFK(kc) \
    acc0 = mfma16(A0_##kc, hb##kc, acc0); acc1 = mfma16(A1_##kc, hb##kc, acc1); \
    acc2 = mfma16(A2_##kc, hb##kc, acc2); acc3 = mfma16(A3_##kc, hb##kc, acc3); \
    acc4 = mfma16(A4_##kc, hb##kc, acc4); acc5 = mfma16(A5_##kc, hb##kc, acc5); \
    acc6 = mfma16(A6_##kc, hb##kc, acc6); acc7 = mfma16(A7_##kc, hb##kc, acc7);
    MFK(0) MFK(1) MFK(2) MFK(3) MFK(4) MFK(5) MFK(6) MFK(7)
#undef MFK

    const int zb = (w << 8) + ((l >> 4) << 2);
#define ZW(rt) if ((l & 15) == 0) *(f32x4*)&z_sh[zb + (rt) * 16] = acc##rt;
    ZW(0) ZW(1) ZW(2) ZW(3) ZW(4) ZW(5) ZW(6) ZW(7)
#undef ZW

    // consume batch 1
    asm volatile("s_waitcnt vmcnt(0)" ::: "memory");
    __builtin_amdgcn_sched_barrier(0);
    f32x4 sacc0 = {0.f,0.f,0.f,0.f}, sacc1 = {0.f,0.f,0.f,0.f};
    f32x4 sacc2 = {0.f,0.f,0.f,0.f}, sacc3 = {0.f,0.f,0.f,0.f};
#define SMK(kc) \
    sacc0 = mfma16(S0_##kc, hb##kc, sacc0); sacc1 = mfma16(S1_##kc, hb##kc, sacc1); \
    sacc2 = mfma16(S2_##kc, hb##kc, sacc2); sacc3 = mfma16(S3_##kc, hb##kc, sacc3);
    SMK(0) SMK(1) SMK(2) SMK(3) SMK(4) SMK(5) SMK(6) SMK(7)
    if ((l & 15) == 0) {
      *(f32x4*)&z_sh[zb + 8  * 16] = sacc0;
      *(f32x4*)&z_sh[zb + 9  * 16] = sacc1;
      *(f32x4*)&z_sh[zb + 10 * 16] = sacc2;
      *(f32x4*)&z_sh[zb + 11 * 16] = sacc3;
    }

    // batch 2 (tiles 12..15) into the same registers
    SLOAD8(S0, sb12a, sb12b)
    SLOAD8(S1, sb13a, sb13b)
    SLOAD8(S2, sb14a, sb14b)
    SLOAD8(S3, sb15a, sb15b)
    asm volatile("s_waitcnt vmcnt(0)" ::: "memory");
    __builtin_amdgcn_sched_barrier(0);
    sacc0 = (f32x4){0.f,0.f,0.f,0.f}; sacc1 = (f32x4){0.f,0.f,0.f,0.f};
    sacc2 = (f32x4){0.f,0.f,0.f,0.f}; sacc3 = (f32x4){0.f,0.f,0.f,0.f};
    SMK(0) SMK(1) SMK(2) SMK(3) SMK(4) SMK(5) SMK(6) SMK(7)
#undef SMK
    if ((l & 15) == 0) {
      *(f32x4*)&z_sh[zb + 12 * 16] = sacc0;
      *(f32x4*)&z_sh[zb + 13 * 16] = sacc1;
      *(f32x4*)&z_sh[zb + 14 * 16] = sacc2;
      *(f32x4*)&z_sh[zb + 15 * 16] = sacc3;
    }

    __syncthreads();

    // gate phase (all 256 threads)
    {
      float zi = z_sh[j]       + xpi;
      float zf = z_sh[j + 256] + xpf;
      float zg = z_sh[j + 512] + xpg;
      float zo = z_sh[j + 768] + xpo;
      float ig = fsig(zi), fg = fsig(zf), gg = ftanh(zg), og = fsig(zo);
      c = fg * c + ig * gg;
      float h = og * ftanh(c);
      out[(size_t)t * hstride + j] = h;
      h_sh[j] = (_Float16)h;
      int sn = (s + 1 < T) ? (s + 1) : s;
      int tn = rev ? (T - 1 - sn) : sn;
      xpi = Xp[(size_t)tn * GATE + j];
      xpf = Xp[(size_t)tn * GATE + j + 256];
      xpg = Xp[(size_t)tn * GATE + j + 512];
      xpo = Xp[(size_t)tn * GATE + j + 768];
    }
    __syncthreads();
  }
}

// ---------------------------------------------------------------------------
extern "C" void kernel_launch(void* const* d_in, const int* in_sizes, int n_in,
                              void* d_out, int out_size, void* d_ws, size_t ws_size,
                              hipStream_t stream) {
  (void)in_sizes; (void)n_in; (void)out_size; (void)ws_size;
  const float* inputs = (const float*)d_in[0];
  const int*   edges  = (const int*)d_in[1];
  const float* memory = (const float*)d_in[2];
  const float* Wl_ih  = (const float*)d_in[3];
  const float* Wl_hh  = (const float*)d_in[4];
  const float* bl     = (const float*)d_in[5];
  const float* Wh_ih  = (const float*)d_in[6];
  const float* Wh_hh  = (const float*)d_in[7];
  const float* bh     = (const float*)d_in[8];
  const float* Win    = (const float*)d_in[9];
  const float* bin_   = (const float*)d_in[10];
  const float* We     = (const float*)d_in[11];
  const float* be     = (const float*)d_in[12];
  const float* Wn_ih  = (const float*)d_in[13];
  const float* Wn_hh  = (const float*)d_in[14];
  const float* bn     = (const float*)d_in[15];
  const float* Wmem   = (const float*)d_in[16];
  const float* bmem   = (const float*)d_in[17];
  const float* Wc_ih  = (const float*)d_in[18];
  const float* Wc_hh  = (const float*)d_in[19];
  const float* bc     = (const float*)d_in[20];
  const float* Wout   = (const float*)d_in[21];
  const float* bout   = (const float*)d_in[22];

  float* out_ptr = (float*)d_out;                       // [T][256]
  float* memvec  = out_ptr + (size_t)T_LEN * OUT_N;     // [T][256]

  // ---- workspace carve ----
  char* base = (char*)d_ws;
  size_t off = 0;
  auto carve = [&](size_t nbytes) -> void* {
    void* p = base + off; off += (nbytes + 255) & ~(size_t)255; return p;
  };
  float* XpA    = (float*)carve((size_t)T_LEN * GATE * 4);
  float* XpB    = (float*)carve((size_t)T_LEN * GATE * 4);
  float* XpC    = (float*)carve((size_t)T_LEN * GATE * 4);
  float* XpN    = (float*)carve((size_t)T_LEN * GATE * 4);
  float* lower  = (float*)carve((size_t)T_LEN * 512 * 4);
  float* higher = (float*)carve((size_t)T_LEN * 512 * 4);
  float* nodesA = (float*)carve((size_t)T_LEN * 256 * 4);
  float* nodesB = (float*)carve((size_t)T_LEN * 256 * 4);
  float* pairb  = (float*)carve((size_t)T_LEN * 512 * 4);
  float* ehb    = (float*)carve((size_t)T_LEN * 256 * 4);
  float* ctrlh  = (float*)carve((size_t)T_LEN * 256 * 4);
  u32x4* Wf_all = (u32x4*)carve((size_t)9 * 32768 * 16);

  // ---- fragment prep (9 recurrent matrices) ----
  PrepSrcs ps;
  ps.p[0] = Wl_hh;            ps.p[1] = Wl_hh + 262144;
  ps.p[2] = Wh_hh;            ps.p[3] = Wh_hh + 262144;
  ps.p[4] = Wn_hh;            ps.p[5] = Wn_hh + 262144;
  ps.p[6] = Wn_hh + 524288;   ps.p[7] = Wn_hh + 786432;
  ps.p[8] = Wc_hh;
  prep_frags<<<9 * 32768 / 256, 256, 0, stream>>>(ps, Wf_all);
  auto Wf = [&](int m) { return (const u32x4*)(Wf_all + (size_t)m * 32768); };

  auto gemm = [&](float* C, int ldc, const float* A, int lda,
                  const float* W, int ldw, const float* bias, const float* addC,
                  int M, int N, int K) {
    dim3 g(N / 64, M / 64);
    gemm_kernel<<<g, 256, 0, stream>>>(A, lda, W, ldw, bias, addC, C, ldc, M, N, K);
  };
  auto scan3 = [&](ScanDesc a, ScanDesc b, ScanDesc c, int nblk) {
    lstm_scan_mfma<<<nblk, 256, 0, stream>>>(a, b, c, T_LEN);
  };
  ScanDesc dummy = {};

  // ---- G0: lower Xp + node0 Xp ----
  gemm(XpA, GATE, inputs, IN_F, Wl_ih,               IN_F, bl,        nullptr, T_LEN, GATE, IN_F);
  gemm(XpB, GATE, inputs, IN_F, Wl_ih + GATE * IN_F, IN_F, bl + GATE, nullptr, T_LEN, GATE, IN_F);
  gemm(nodesA, 256, inputs, IN_F, Win, IN_F, bin_, nullptr, T_LEN, 256, IN_F);
  gather_kernel<<<T_LEN, 512, 0, stream>>>(nodesA, edges, pairb);
  gemm(ehb, 256, pairb, 512, We + (size_t)0 * HID * 512, 512, be + 0 * HID, nullptr, T_LEN, 256, 512);
  gemm(XpN, GATE, inputs, IN_F, Wn_ih + (size_t)0 * GATE * 512,       512, bn + 0 * GATE, nullptr, T_LEN, GATE, IN_F);
  gemm(XpN, GATE, ehb,    256,  Wn_ih + (size_t)0 * GATE * 512 + 256, 512, nullptr,       XpN,     T_LEN, GATE, 256);

  // ---- Slot1: lower fwd/bwd + node0 ----
  scan3({XpA, Wf(0), lower,       0, 512},
        {XpB, Wf(1), lower + 256, 1, 512},
        {XpN, Wf(4), nodesB,      0, 256}, 3);

  // ---- G1: higher Xp + node1 Xp ----
  gemm(XpA, GATE, lower, 512, Wh_ih,              512, bh,        nullptr, T_LEN, GATE, 512);
  gemm(XpB, GATE, lower, 512, Wh_ih + GATE * 512, 512, bh + GATE, nullptr, T_LEN, GATE, 512);
  gather_kernel<<<T_LEN, 512, 0, stream>>>(nodesB, edges, pairb);
  gemm(ehb, 256, pairb, 512, We + (size_t)1 * HID * 512, 512, be + 1 * HID, nullptr, T_LEN, 256, 512);
  gemm(XpN, GATE, inputs, IN_F, Wn_ih + (size_t)1 * GATE * 512,       512, bn + 1 * GATE, nullptr, T_LEN, GATE, IN_F);
  gemm(XpN, GATE, ehb,    256,  Wn_ih + (size_t)1 * GATE * 512 + 256, 512, nullptr,       XpN,     T_LEN, GATE, 256);

  // ---- Slot2: higher fwd/bwd + node1 ----
  scan3({XpA, Wf(2), higher,       0, 512},
        {XpB, Wf(3), higher + 256, 1, 512},
        {XpN, Wf(5), nodesA,       0, 256}, 3);

  // ---- G2: ctrl Xp + node2 Xp ----
  gemm(XpC, GATE, inputs, IN_F, Wc_ih,       896, bc,      nullptr, T_LEN, GATE, IN_F);
  gemm(XpC, GATE, memory, 128,  Wc_ih + 768, 896, nullptr, XpC,     T_LEN, GATE, 128);
  gemm(XpC, GATE, higher, 512,  Wc_ih + 256, 896, nullptr, XpC,     T_LEN, GATE, 512);
  gather_kernel<<<T_LEN, 512, 0, stream>>>(nodesA, edges, pairb);
  gemm(ehb, 256, pairb, 512, We + (size_t)2 * HID * 512, 512, be + 2 * HID, nullptr, T_LEN, 256, 512);
  gemm(XpN, GATE, inputs, IN_F, Wn_ih + (size_t)2 * GATE * 512,       512, bn + 2 * GATE, nullptr, T_LEN, GATE, IN_F);
  gemm(XpN, GATE, ehb,    256,  Wn_ih + (size_t)2 * GATE * 512 + 256, 512, nullptr,       XpN,     T_LEN, GATE, 256);

  // ---- Slot3: node2 + ctrl ----
  scan3({XpN, Wf(6), nodesB, 0, 256},
        {XpC, Wf(8), ctrlh,  0, 256}, dummy, 2);

  // ---- G3: node3 Xp ----
  gather_kernel<<<T_LEN, 512, 0, stream>>>(nodesB, edges, pairb);
  gemm(ehb, 256, pairb, 512, We + (size_t)3 * HID * 512, 512, be + 3 * HID, nullptr, T_LEN, 256, 512);
  gemm(XpN, GATE, inputs, IN_F, Wn_ih + (size_t)3 * GATE * 512,       512, bn + 3 * GATE, nullptr, T_LEN, GATE, IN_F);
  gemm(XpN, GATE, ehb,    256,  Wn_ih + (size_t)3 * GATE * 512 + 256, 512, nullptr,       XpN,     T_LEN, GATE, 256);

  // ---- Slot4: node3 ----
  scan3({XpN, Wf(7), nodesA, 0, 256}, dummy, dummy, 1);

  // ---- finals ----
  gemm(memvec,  256, nodesA, 256, Wmem, HID, bmem, nullptr, T_LEN, 256, HID);
  gemm(out_ptr, 256, ctrlh,  256, Wout, HID, bout, nullptr, T_LEN, 256, HID);
}